// Round 3
// baseline (555.061 us; speedup 1.0000x reference)
//
#include <hip/hip_runtime.h>
#include <math.h>

// Problem constants (fixed by reference): B=1024, NMAX=128, D=256, NUM=4
#define BB   1024
#define DD   256
#define LOGD 5.5451774444795624753f   // log(256)

typedef __attribute__((ext_vector_type(8))) short short8;   // 8 bf16 = 4 VGPRs
typedef __attribute__((ext_vector_type(4))) float f32x4;    // MFMA acc

__device__ __forceinline__ float wave_max(float v){
  #pragma unroll
  for (int off=32; off>0; off>>=1) v = fmaxf(v, __shfl_xor(v, off, 64));
  return v;
}
__device__ __forceinline__ float wave_sum(float v){
  #pragma unroll
  for (int off=32; off>0; off>>=1) v += __shfl_xor(v, off, 64);
  return v;
}
__device__ __forceinline__ float fast_tanh(float x){
  return 1.0f - 2.0f/(__expf(2.0f*x)+1.0f);
}
__device__ __forceinline__ unsigned short f2bf(float f){
  unsigned int u = __float_as_uint(f);
  unsigned int r = u + 0x7FFFu + ((u >> 16) & 1u);   // RNE
  return (unsigned short)(r >> 16);
}
// s16 fixed-point codec for log-domain LDS state (range +-64, quantum 2^-9)
__device__ __forceinline__ short enc16(float a){
  float c = fminf(fmaxf(a*512.f, -32767.f), 32767.f);
  return (short)__float2int_rn(c);
}
__device__ __forceinline__ float dec16(short v){ return (float)v * (1.f/512.f); }
// order-preserving float<->uint map for LDS atomicMax
__device__ __forceinline__ unsigned omap(float f){
  unsigned u = __float_as_uint(f);
  return (u & 0x80000000u) ? ~u : (u | 0x80000000u);
}
__device__ __forceinline__ float ounmap(unsigned v){
  return (v & 0x80000000u) ? __uint_as_float(v ^ 0x80000000u) : __uint_as_float(~v);
}

// ---- K1: segment bounds via binary search (batch is sorted) ----
__global__ void k_bounds(const int* __restrict__ batch, int T, int* __restrict__ starts){
  int b = blockIdx.x*blockDim.x + threadIdx.x;
  if (b > BB) return;
  int lo = 0, hi = T;
  while (lo < hi){ int mid = (lo+hi)>>1; if (batch[mid] < b) lo = mid+1; else hi = mid; }
  starts[b] = lo;
}

// ---- K1b: scalar parameter chain ----
__global__ void k_params(const float* __restrict__ rho, const float* __restrict__ a1,
                         const float* __restrict__ a2, const float* __restrict__ a3,
                         float* __restrict__ P){
  if (threadIdx.x != 0 || blockIdx.x != 0) return;
  float lm = -LOGD, z1 = 0.f;
  for (int k=0;k<4;k++){
    float r  = log1pf(expf(rho[k]));
    float b1 = log1pf(expf(a1[k]));
    float b2 = log1pf(expf(a2[k]));
    float b3 = log1pf(expf(a3[k]));
    P[k]    = r;
    P[4+k]  = 1.f/(b1+r);
    P[8+k]  = 1.f/(b2+r);
    P[12+k] = lm;              // mu used by S-update of iteration k
    P[16+k] = b3;
    P[20+k] = 1.f/(b3+r);
    float lmn = (b3*(-LOGD) - z1 + r*lm)/(b3+r);
    z1 += r*(expf(lmn)-expf(lm));
    lm = lmn;
  }
}

// ---- K2: fused MLP via bf16 MFMA, K-tiled for occupancy ----
// Tile M=64 x N=128 (hidden), BK=64, 256 thr (4 waves). LDS ~28 KB -> 5 blk/CU.
// grid = (4 hidden-tiles, T/64 row-tiles): .x fastest so the 4 blocks sharing
// one x row-tile dispatch back-to-back (L2/L3 reuse of x).
#define LP2 72   // LDS row stride in shorts (144 B = 36 banks -> 2-way max, free)
__global__ __launch_bounds__(256, 5) void k_mlp(
    const float* __restrict__ x, const float* __restrict__ W1,
    const float* __restrict__ W2, float* __restrict__ logits, int T)
{
  __shared__ unsigned short Xs[64*LP2];    //  9216 B
  __shared__ unsigned short Ws[128*LP2];   // 18432 B
  __shared__ float lred[64];
  const int by = blockIdx.x;   // hidden tile 0..3
  const int bx = blockIdx.y;   // row tile
  const int tid = threadIdx.x;
  if (tid < 64) lred[tid] = 0.f;

  const int l = tid & 63;
  const int wn = tid >> 6;            // wave 0..3 = N quarter (32 hidden each)
  const int lr = l & 15, quad = l >> 4;
  const int srow = tid >> 2;          // staging row 0..63
  const int sseg = tid & 3;           // 16-float segment

  f32x4 acc[4][2];
  #pragma unroll
  for (int mi=0;mi<4;mi++)
    #pragma unroll
    for (int ni=0;ni<2;ni++) acc[mi][ni] = (f32x4){0.f,0.f,0.f,0.f};

  for (int kt=0; kt<4; kt++){
    const int k0 = kt*64 + sseg*16;
    // stage X tile (64 rows x 64 k)
    {
      const int grow = bx*64 + srow;
      #pragma unroll
      for (int i=0;i<4;i++){
        float4 v = make_float4(0.f,0.f,0.f,0.f);
        if (grow < T) v = *(const float4*)(x + (size_t)grow*DD + k0 + i*4);
        ushort4 pv = make_ushort4(f2bf(v.x), f2bf(v.y), f2bf(v.z), f2bf(v.w));
        *(ushort4*)&Xs[srow*LP2 + sseg*16 + i*4] = pv;
      }
    }
    // stage W tile (128 rows x 64 k)
    #pragma unroll
    for (int h=0; h<2; h++){
      const int wrow = h*64 + srow;
      #pragma unroll
      for (int i=0;i<4;i++){
        const float4 v = *(const float4*)(W1 + (size_t)(by*128+wrow)*DD + k0 + i*4);
        ushort4 pv = make_ushort4(f2bf(v.x), f2bf(v.y), f2bf(v.z), f2bf(v.w));
        *(ushort4*)&Ws[wrow*LP2 + sseg*16 + i*4] = pv;
      }
    }
    __syncthreads();
    #pragma unroll
    for (int ks=0; ks<2; ks++){
      short8 afr[4], bfr[2];
      #pragma unroll
      for (int mi=0;mi<4;mi++)
        afr[mi] = *(const short8*)&Xs[(mi*16 + lr)*LP2 + ks*32 + quad*8];
      #pragma unroll
      for (int ni=0;ni<2;ni++)
        bfr[ni] = *(const short8*)&Ws[(wn*32 + ni*16 + lr)*LP2 + ks*32 + quad*8];
      #pragma unroll
      for (int mi=0;mi<4;mi++)
        #pragma unroll
        for (int ni=0;ni<2;ni++)
          acc[mi][ni] = __builtin_amdgcn_mfma_f32_16x16x32_bf16(afr[mi], bfr[ni], acc[mi][ni], 0, 0, 0);
    }
    __syncthreads();
  }

  // epilogue: tanh + dot W2 + reduce over the 16-lane hidden group
  float w2v[2];
  #pragma unroll
  for (int ni=0;ni<2;ni++) w2v[ni] = W2[by*128 + wn*32 + ni*16 + lr];
  #pragma unroll
  for (int mi=0;mi<4;mi++){
    float p[4];
    #pragma unroll
    for (int v=0; v<4; v++){
      p[v] = fast_tanh(acc[mi][0][v])*w2v[0] + fast_tanh(acc[mi][1][v])*w2v[1];
      #pragma unroll
      for (int off=1; off<16; off<<=1) p[v] += __shfl_xor(p[v], off, 64);
    }
    if (lr == 0){
      #pragma unroll
      for (int v=0; v<4; v++)
        atomicAdd(&lred[mi*16 + quad*4 + v], p[v]);
    }
  }
  __syncthreads();
  if (tid < 64){
    const int grow = bx*64 + tid;
    if (grow < T) atomicAdd(logits + grow, lred[tid]);
  }
}

// ---- K3: per-segment softmax -> log(q0 + 1e-8) ----
__global__ void k_seg_softmax(const float* __restrict__ logits, const int* __restrict__ starts,
                              float* __restrict__ lq0)
{
  const int b = blockIdx.x;
  const int start = starts[b], len = starts[b+1]-start;
  const int l = threadIdx.x; // 64 threads = 1 wave
  float v0 = (l      < len) ? logits[start+l]    : -3.0e38f;
  float v1 = (l+64   < len) ? logits[start+l+64] : -3.0e38f;
  float m = wave_max(fmaxf(v0,v1));
  float e0 = (l    < len) ? __expf(v0-m) : 0.f;
  float e1 = (l+64 < len) ? __expf(v1-m) : 0.f;
  float s = wave_sum(e0+e1);
  float inv = 1.f/(s + 1e-16f);
  if (l      < len) lq0[start+l]    = __logf(e0*inv + 1e-8f);
  if (l+64   < len) lq0[start+l+64] = __logf(e1*inv + 1e-8f);
}

// ---- K4: BADMM solver, one block per batch ----
// A (log_s / log_t) in LDS as s16 fixed-point (64 KB); column reductions via
// LDS atomics (colm/cols, 2 KB) -> total LDS ~66 KB -> 2 blocks/CU.
// __launch_bounds__(1024,8) caps VGPR at 64 so both 16-wave blocks fit.
__global__ __launch_bounds__(1024, 8) void k_solver(
    const float* __restrict__ x, const float* __restrict__ lq0,
    const int* __restrict__ starts, const float* __restrict__ P,
    float* __restrict__ out)
{
  __shared__ short A16[128*DD];     // 64 KB
  __shared__ unsigned colm[DD];     // 1 KB
  __shared__ float    cols[DD];     // 1 KB
  const int b = blockIdx.x;
  const int start = starts[b];
  const int len = starts[b+1] - start;
  const int tid = threadIdx.x;
  const int w = tid >> 6, l = tid & 63;
  const int n0 = w*8;
  int nv = len - n0; nv = nv < 0 ? 0 : (nv > 8 ? 8 : nv);

  float z[8][4];
  float eta[8], z2r[8];
  #pragma unroll
  for (int r=0;r<8;r++){
    #pragma unroll
    for (int j=0;j<4;j++) z[r][j]=0.f;
    z2r[r]=0.f; eta[r]=0.f;
  }
  #pragma unroll
  for (int r=0;r<8;r++){
    if (r < nv){
      const float v = lq0[start + n0 + r];
      eta[r] = v;
      const short q = enc16(v - LOGD);
      const int base = (n0+r)*DD + l;
      #pragma unroll
      for (int j=0;j<4;j++) A16[base + 64*j] = q;
    }
  }

  for (int k=0;k<3;k++){
    const float rk = P[k], ib1 = P[4+k], ib2 = P[8+k], muk = P[12+k];
    const float b3 = P[16+k], ib3r = P[20+k];
    __syncthreads();   // (a) close prev iteration's cols/colm readers
    // ---- P1: T-update (row LSE over D via shuffles), A: log_s -> log_t ----
    #pragma unroll
    for (int r=0;r<8;r++){
      if (r < nv){
        const int n = n0 + r;
        const float* xp = x + (size_t)(start+n)*DD + l;
        const int base = n*DD + l;
        float y[4];
        #pragma unroll
        for (int j=0;j<4;j++) y[j] = (xp[64*j] - z[r][j] + rk*dec16(A16[base+64*j])) * ib2;
        float m = fmaxf(fmaxf(y[0],y[1]), fmaxf(y[2],y[3]));
        m = wave_max(m);
        float se = 0.f;
        #pragma unroll
        for (int j=0;j<4;j++) se += __expf(y[j]-m);
        se = wave_sum(se);
        const float lse = m + __logf(se);
        const float e = eta[r];
        #pragma unroll
        for (int j=0;j<4;j++) A16[base+64*j] = enc16(e + y[j] - lse);
      }
    }
    if (tid < DD){ colm[tid] = 0u; cols[tid] = 0.f; }
    __syncthreads();   // (b) init visible
    // ---- P2a: column max via LDS atomicMax (ordered-uint) ----
    {
      float mp[4] = {-3.0e38f,-3.0e38f,-3.0e38f,-3.0e38f};
      #pragma unroll
      for (int r=0;r<8;r++){
        if (r < nv){
          const int base = (n0+r)*DD + l;
          #pragma unroll
          for (int j=0;j<4;j++){
            const float ys = (z[r][j] + rk*dec16(A16[base+64*j])) * ib1;
            mp[j] = fmaxf(mp[j], ys);
          }
        }
      }
      if (nv > 0){
        #pragma unroll
        for (int j=0;j<4;j++) atomicMax(&colm[l+64*j], omap(mp[j]));
      }
    }
    __syncthreads();   // (c) colm final
    // ---- P2b: column sum-exp via LDS atomicAdd ----
    float cm[4];
    #pragma unroll
    for (int j=0;j<4;j++) cm[j] = ounmap(colm[l+64*j]);
    {
      float sp[4] = {0.f,0.f,0.f,0.f};
      #pragma unroll
      for (int r=0;r<8;r++){
        if (r < nv){
          const int base = (n0+r)*DD + l;
          #pragma unroll
          for (int j=0;j<4;j++){
            const float ys = (z[r][j] + rk*dec16(A16[base+64*j])) * ib1;
            sp[j] += __expf(ys - cm[j]);
          }
        }
      }
      if (nv > 0){
        #pragma unroll
        for (int j=0;j<4;j++) atomicAdd(&cols[l+64*j], sp[j]);
      }
    }
    __syncthreads();   // (d) cols final
    float lsc[4];
    #pragma unroll
    for (int j=0;j<4;j++) lsc[j] = cm[j] + __logf(cols[l+64*j]);
    // ---- P3: S-update + dual ascent, A: log_t -> log_s_new ----
    #pragma unroll
    for (int r=0;r<8;r++){
      if (r < nv){
        const int base = (n0+r)*DD + l;
        #pragma unroll
        for (int j=0;j<4;j++){
          const float lt  = dec16(A16[base+64*j]);
          const float ys  = (z[r][j] + rk*lt) * ib1;
          const float lsn = muk + ys - lsc[j];
          const float s = __expf(lsn);
          const float t = __expf(lt);
          z[r][j] += rk*(t - s);
          A16[base+64*j] = enc16(lsn);
        }
        const float lqr = lq0[start + n0 + r];
        const float en = (b3*lqr - z2r[r] + rk*eta[r]) * ib3r;
        z2r[r] += rk*(__expf(en) - __expf(eta[r]));
        eta[r] = en;
      }
    }
  }
  // ---- k=3: T-update only + output (t = ey * exp(eta)/se, row-scale trick) ----
  {
    const float rk = P[3], ib2 = P[8+3];
    float op[4] = {0.f,0.f,0.f,0.f};
    #pragma unroll
    for (int r=0;r<8;r++){
      if (r < nv){
        const int n = n0 + r;
        const float* xp = x + (size_t)(start+n)*DD + l;
        const int base = n*DD + l;
        float y[4], xv[4];
        #pragma unroll
        for (int j=0;j<4;j++){
          xv[j] = xp[64*j];
          y[j] = (xv[j] - z[r][j] + rk*dec16(A16[base+64*j])) * ib2;
        }
        float m = fmaxf(fmaxf(y[0],y[1]), fmaxf(y[2],y[3]));
        m = wave_max(m);
        float ey[4], se = 0.f;
        #pragma unroll
        for (int j=0;j<4;j++){ ey[j] = __expf(y[j]-m); se += ey[j]; }
        se = wave_sum(se);
        const float rs = __expf(eta[r] - __logf(se));  // exp(eta)/se
        #pragma unroll
        for (int j=0;j<4;j++) op[j] += xv[j]*ey[j]*rs;
      }
    }
    __syncthreads();
    if (tid < DD) cols[tid] = 0.f;
    __syncthreads();
    #pragma unroll
    for (int j=0;j<4;j++) atomicAdd(&cols[l+64*j], op[j]);
    __syncthreads();
    if (tid < DD) out[(size_t)b*DD + tid] = 256.0f * cols[tid];
  }
}

extern "C" void kernel_launch(void* const* d_in, const int* in_sizes, int n_in,
                              void* d_out, int out_size, void* d_ws, size_t ws_size,
                              hipStream_t stream) {
  const float* x    = (const float*)d_in[0];
  const int*   batch= (const int*)d_in[1];
  const float* W1   = (const float*)d_in[2];
  const float* W2   = (const float*)d_in[3];
  const float* rho  = (const float*)d_in[4];
  const float* a1   = (const float*)d_in[5];
  const float* a2   = (const float*)d_in[6];
  const float* a3   = (const float*)d_in[7];
  float* out = (float*)d_out;
  const int T = in_sizes[1];   // total ragged rows

  float* logits = (float*)d_ws;            // T floats
  float* lq0    = logits + T;              // T floats
  int*   starts = (int*)(lq0 + T);         // B+1 ints
  float* P      = (float*)(starts + 1028); // 24 floats

  k_bounds<<<dim3((BB+1+255)/256), 256, 0, stream>>>(batch, T, starts);
  k_params<<<1, 64, 0, stream>>>(rho, a1, a2, a3, P);
  hipMemsetAsync(logits, 0, (size_t)T*sizeof(float), stream);
  k_mlp<<<dim3(4, (T+63)/64), 256, 0, stream>>>(x, W1, W2, logits, T);
  k_seg_softmax<<<BB, 64, 0, stream>>>(logits, starts, lq0);
  k_solver<<<BB, 1024, 0, stream>>>(x, lq0, starts, P, out);
}

// Round 4
// 469.853 us; speedup vs baseline: 1.1814x; 1.1814x over previous
//
#include <hip/hip_runtime.h>
#include <math.h>

// Problem constants (fixed by reference): B=1024, NMAX=128, D=256, NUM=4
#define BB   1024
#define DD   256
#define LOGD 5.5451774444795624753f   // log(256)

typedef __attribute__((ext_vector_type(8))) short short8;   // 8 bf16 = 4 VGPRs
typedef __attribute__((ext_vector_type(4))) float f32x4;    // MFMA acc

__device__ __forceinline__ float wave_sum(float v){
  #pragma unroll
  for (int off=32; off>0; off>>=1) v += __shfl_xor(v, off, 64);
  return v;
}
__device__ __forceinline__ float wave_max(float v){
  #pragma unroll
  for (int off=32; off>0; off>>=1) v = fmaxf(v, __shfl_xor(v, off, 64));
  return v;
}
__device__ __forceinline__ float fast_tanh(float x){
  return 1.0f - 2.0f/(__expf(2.0f*x)+1.0f);
}
__device__ __forceinline__ unsigned short f2bf(float f){
  unsigned int u = __float_as_uint(f);
  unsigned int r = u + 0x7FFFu + ((u >> 16) & 1u);   // RNE
  return (unsigned short)(r >> 16);
}
// s16 fixed-point codec for log-domain LDS state (range +-64, quantum 2^-9)
__device__ __forceinline__ short enc16(float a){
  float c = fminf(fmaxf(a*512.f, -32767.f), 32767.f);
  return (short)__float2int_rn(c);
}
__device__ __forceinline__ float dec16(short v){ return (float)v * (1.f/512.f); }

// ---- K1: segment bounds via binary search (batch is sorted) ----
__global__ void k_bounds(const int* __restrict__ batch, int T, int* __restrict__ starts){
  int b = blockIdx.x*blockDim.x + threadIdx.x;
  if (b > BB) return;
  int lo = 0, hi = T;
  while (lo < hi){ int mid = (lo+hi)>>1; if (batch[mid] < b) lo = mid+1; else hi = mid; }
  starts[b] = lo;
}

// ---- K1b: scalar parameter chain ----
__global__ void k_params(const float* __restrict__ rho, const float* __restrict__ a1,
                         const float* __restrict__ a2, const float* __restrict__ a3,
                         float* __restrict__ P){
  if (threadIdx.x != 0 || blockIdx.x != 0) return;
  float lm = -LOGD, z1 = 0.f;
  for (int k=0;k<4;k++){
    float r  = log1pf(expf(rho[k]));
    float b1 = log1pf(expf(a1[k]));
    float b2 = log1pf(expf(a2[k]));
    float b3 = log1pf(expf(a3[k]));
    P[k]    = r;
    P[4+k]  = 1.f/(b1+r);
    P[8+k]  = 1.f/(b2+r);
    P[12+k] = lm;              // mu used by S-update of iteration k
    P[16+k] = b3;
    P[20+k] = 1.f/(b3+r);
    float lmn = (b3*(-LOGD) - z1 + r*lm)/(b3+r);
    z1 += r*(expf(lmn)-expf(lm));
    lm = lmn;
  }
}

// ---- K1c: one-time W1 fp32 -> bf16 cast (512x256) ----
__global__ void k_castw(const float* __restrict__ W1, unsigned short* __restrict__ w1b){
  const int t = blockIdx.x*256 + threadIdx.x;   // 16384 threads
  #pragma unroll
  for (int i=0;i<2;i++){
    const int idx = (t*2 + i)*4;                // float4 index
    const float4 v = *(const float4*)(W1 + idx);
    *(ushort4*)(w1b + idx) = make_ushort4(f2bf(v.x), f2bf(v.y), f2bf(v.z), f2bf(v.w));
  }
}

// ---- K2: fused MLP via bf16 MFMA ----
// Tile M=64 (rows) x N=256 (hidden half), BK=64, 256 thr (4 waves).
// LDS ~46.6 KB -> 3 blocks/CU. W1 pre-cast to bf16 (no per-tile conversion).
// x read only 2x (two hidden halves). Wave tile 64x64 = 4x4 acc (64 AGPRs).
#define LPX 72   // LDS row stride in shorts (144 B, 16B-aligned; 2-way bank alias = free)
__global__ __launch_bounds__(256, 3) void k_mlp(
    const float* __restrict__ x, const unsigned short* __restrict__ w1b,
    const float* __restrict__ W2, float* __restrict__ logits, int T)
{
  __shared__ unsigned short Xs[64*LPX];    //  9216 B
  __shared__ unsigned short Ws[256*LPX];   // 36864 B
  __shared__ float lred[64];
  const int hh = blockIdx.x;   // hidden half 0..1
  const int bx = blockIdx.y;   // row tile
  const int tid = threadIdx.x;
  if (tid < 64) lred[tid] = 0.f;

  const int l = tid & 63;
  const int wn = tid >> 6;            // wave 0..3 = N quarter (64 hidden each)
  const int lr = l & 15, quad = l >> 4;
  const int srow = tid >> 2;          // x-staging row 0..63
  const int sseg = tid & 3;           // 16-float segment
  const int wrow0 = tid >> 3;         // w-staging row base
  const int wch  = tid & 7;           // 8-short chunk

  f32x4 acc[4][4];
  #pragma unroll
  for (int mi=0;mi<4;mi++)
    #pragma unroll
    for (int ni=0;ni<4;ni++) acc[mi][ni] = (f32x4){0.f,0.f,0.f,0.f};

  for (int kt=0; kt<4; kt++){
    const int k0 = kt*64;
    // stage X tile (64 rows x 64 k, fp32 -> bf16)
    {
      const int grow = bx*64 + srow;
      #pragma unroll
      for (int i=0;i<4;i++){
        float4 v = make_float4(0.f,0.f,0.f,0.f);
        if (grow < T) v = *(const float4*)(x + (size_t)grow*DD + k0 + sseg*16 + i*4);
        *(ushort4*)&Xs[srow*LPX + sseg*16 + i*4] =
            make_ushort4(f2bf(v.x), f2bf(v.y), f2bf(v.z), f2bf(v.w));
      }
    }
    // stage W tile (256 rows x 64 k, already bf16)
    #pragma unroll
    for (int rep=0; rep<8; rep++){
      const int wrow = rep*32 + wrow0;
      *(short8*)&Ws[wrow*LPX + wch*8] =
          *(const short8*)(w1b + (size_t)(hh*256 + wrow)*DD + k0 + wch*8);
    }
    __syncthreads();
    #pragma unroll
    for (int ks=0; ks<2; ks++){
      short8 afr[4], bfr[4];
      #pragma unroll
      for (int mi=0;mi<4;mi++)
        afr[mi] = *(const short8*)&Xs[(mi*16 + lr)*LPX + ks*32 + quad*8];
      #pragma unroll
      for (int ni=0;ni<4;ni++)
        bfr[ni] = *(const short8*)&Ws[(wn*64 + ni*16 + lr)*LPX + ks*32 + quad*8];
      #pragma unroll
      for (int mi=0;mi<4;mi++)
        #pragma unroll
        for (int ni=0;ni<4;ni++)
          acc[mi][ni] = __builtin_amdgcn_mfma_f32_16x16x32_bf16(afr[mi], bfr[ni], acc[mi][ni], 0, 0, 0);
    }
    __syncthreads();
  }

  // epilogue: tanh + dot W2 + reduce over the 16-lane hidden group
  float w2v[4];
  #pragma unroll
  for (int ni=0;ni<4;ni++) w2v[ni] = W2[hh*256 + wn*64 + ni*16 + lr];
  #pragma unroll
  for (int mi=0;mi<4;mi++){
    float p[4];
    #pragma unroll
    for (int v=0; v<4; v++){
      p[v] = fast_tanh(acc[mi][0][v])*w2v[0] + fast_tanh(acc[mi][1][v])*w2v[1]
           + fast_tanh(acc[mi][2][v])*w2v[2] + fast_tanh(acc[mi][3][v])*w2v[3];
      #pragma unroll
      for (int off=1; off<16; off<<=1) p[v] += __shfl_xor(p[v], off, 64);
    }
    if (lr == 0){
      #pragma unroll
      for (int v=0; v<4; v++)
        atomicAdd(&lred[mi*16 + quad*4 + v], p[v]);
    }
  }
  __syncthreads();
  if (tid < 64){
    const int grow = bx*64 + tid;
    if (grow < T) atomicAdd(logits + grow, lred[tid]);
  }
}

// ---- K3: per-segment softmax -> log(q0 + 1e-8) ----
__global__ void k_seg_softmax(const float* __restrict__ logits, const int* __restrict__ starts,
                              float* __restrict__ lq0)
{
  const int b = blockIdx.x;
  const int start = starts[b], len = starts[b+1]-start;
  const int l = threadIdx.x; // 64 threads = 1 wave
  float v0 = (l      < len) ? logits[start+l]    : -3.0e38f;
  float v1 = (l+64   < len) ? logits[start+l+64] : -3.0e38f;
  float m = wave_max(fmaxf(v0,v1));
  float e0 = (l    < len) ? __expf(v0-m) : 0.f;
  float e1 = (l+64 < len) ? __expf(v1-m) : 0.f;
  float s = wave_sum(e0+e1);
  float inv = 1.f/(s + 1e-16f);
  if (l      < len) lq0[start+l]    = __logf(e0*inv + 1e-8f);
  if (l+64   < len) lq0[start+l+64] = __logf(e1*inv + 1e-8f);
}

// ---- K4: BADMM solver, one block per batch ----
// A (log_s / log_t) in LDS as s16 fixed-point (64 KB). All exp args are bounded
// above (~+7): no max-subtraction needed anywhere -> the column-max pass is
// deleted and the column sum-exp is fused into the T-update sweep.
// Per iteration: 2 LDS sweeps + 2 barriers (ping-pong cols buffers).
// NOTE: natural VGPR allocation (~60) fits 8 waves/EU; do NOT force
// launch_bounds minimum 8 - round 3 proved that spills z[] to scratch (243 MB).
__global__ __launch_bounds__(1024, 4) void k_solver(
    const float* __restrict__ x, const float* __restrict__ lq0,
    const int* __restrict__ starts, const float* __restrict__ P,
    float* __restrict__ out)
{
  __shared__ short A16[128*DD];     // 64 KB
  __shared__ float cols[2][DD];     // 2 KB ping-pong
  const int b = blockIdx.x;
  const int start = starts[b];
  const int len = starts[b+1] - start;
  const int tid = threadIdx.x;
  const int w = tid >> 6, l = tid & 63;
  const int n0 = w*8;
  int nv = len - n0; nv = nv < 0 ? 0 : (nv > 8 ? 8 : nv);

  float z[8][4];
  float eta[8], z2r[8];
  #pragma unroll
  for (int r=0;r<8;r++){
    #pragma unroll
    for (int j=0;j<4;j++) z[r][j]=0.f;
    z2r[r]=0.f; eta[r]=0.f;
  }
  #pragma unroll
  for (int r=0;r<8;r++){
    if (r < nv){
      const float v = lq0[start + n0 + r];
      eta[r] = v;
      const short q = enc16(v - LOGD);
      const int base = (n0+r)*DD + l;
      #pragma unroll
      for (int j=0;j<4;j++) A16[base + 64*j] = q;
    }
  }
  if (tid < DD){ cols[0][tid] = 0.f; cols[1][tid] = 0.f; }

  for (int k=0;k<3;k++){
    const int p = k & 1;
    const float rk = P[k], ib1 = P[4+k], ib2 = P[8+k], muk = P[12+k];
    const float b3 = P[16+k], ib3r = P[20+k];
    __syncthreads();   // (top) prev P3 stores + cols zero visible
    if (tid < DD) cols[p^1][tid] = 0.f;   // zero NEXT iter's buffer (safe: only cols[p] touched below)
    // ---- fused sweep: T-update (row LSE, no max) + column sum-exp ----
    float sp[4] = {0.f,0.f,0.f,0.f};
    #pragma unroll
    for (int r=0;r<8;r++){
      if (r < nv){
        const int n = n0 + r;
        const float* xp = x + (size_t)(start+n)*DD + l;
        const int base = n*DD + l;
        float y[4];
        #pragma unroll
        for (int j=0;j<4;j++) y[j] = (xp[64*j] - z[r][j] + rk*dec16(A16[base+64*j])) * ib2;
        float se = 0.f;
        #pragma unroll
        for (int j=0;j<4;j++) se += __expf(y[j]);
        se = wave_sum(se);
        const float off = eta[r] - __logf(se);   // lt = off + y
        #pragma unroll
        for (int j=0;j<4;j++){
          const float lt = off + y[j];
          A16[base+64*j] = enc16(lt);
          sp[j] += __expf((z[r][j] + rk*lt) * ib1);
        }
      }
    }
    if (nv > 0){
      #pragma unroll
      for (int j=0;j<4;j++) atomicAdd(&cols[p][l+64*j], sp[j]);
    }
    __syncthreads();   // (mid) cols[p] final
    float lsc[4];
    #pragma unroll
    for (int j=0;j<4;j++) lsc[j] = __logf(cols[p][l+64*j]);   // column LSE (no max needed)
    // ---- S-update + dual ascent, A: log_t -> log_s_new ----
    #pragma unroll
    for (int r=0;r<8;r++){
      if (r < nv){
        const int base = (n0+r)*DD + l;
        #pragma unroll
        for (int j=0;j<4;j++){
          const float lt  = dec16(A16[base+64*j]);
          const float lsn = muk + (z[r][j] + rk*lt) * ib1 - lsc[j];
          z[r][j] += rk*(__expf(lt) - __expf(lsn));
          A16[base+64*j] = enc16(lsn);
        }
        const float lqr = lq0[start + n0 + r];
        const float en = (b3*lqr - z2r[r] + rk*eta[r]) * ib3r;
        z2r[r] += rk*(__expf(en) - __expf(eta[r]));
        eta[r] = en;
      }
    }
  }
  // ---- k=3: T-update only + output (t = exp(eta)/se * exp(y)) ----
  {
    const float rk = P[3], ib2 = P[8+3];
    __syncthreads();   // prev P3 stores visible; cols[1] was zeroed at k=2
    float op[4] = {0.f,0.f,0.f,0.f};
    #pragma unroll
    for (int r=0;r<8;r++){
      if (r < nv){
        const int n = n0 + r;
        const float* xp = x + (size_t)(start+n)*DD + l;
        const int base = n*DD + l;
        float y[4], xv[4];
        #pragma unroll
        for (int j=0;j<4;j++){
          xv[j] = xp[64*j];
          y[j] = (xv[j] - z[r][j] + rk*dec16(A16[base+64*j])) * ib2;
        }
        float ey[4], se = 0.f;
        #pragma unroll
        for (int j=0;j<4;j++){ ey[j] = __expf(y[j]); se += ey[j]; }
        se = wave_sum(se);
        const float rs = __expf(eta[r]) / se;
        #pragma unroll
        for (int j=0;j<4;j++) op[j] += xv[j]*ey[j]*rs;
      }
    }
    if (nv > 0){
      #pragma unroll
      for (int j=0;j<4;j++) atomicAdd(&cols[1][l+64*j], op[j]);
    }
    __syncthreads();
    if (tid < DD) out[(size_t)b*DD + tid] = 256.0f * cols[1][tid];
  }
}

extern "C" void kernel_launch(void* const* d_in, const int* in_sizes, int n_in,
                              void* d_out, int out_size, void* d_ws, size_t ws_size,
                              hipStream_t stream) {
  const float* x    = (const float*)d_in[0];
  const int*   batch= (const int*)d_in[1];
  const float* W1   = (const float*)d_in[2];
  const float* W2   = (const float*)d_in[3];
  const float* rho  = (const float*)d_in[4];
  const float* a1   = (const float*)d_in[5];
  const float* a2   = (const float*)d_in[6];
  const float* a3   = (const float*)d_in[7];
  float* out = (float*)d_out;
  const int T = in_sizes[1];   // total ragged rows

  float* logits = (float*)d_ws;              // T floats
  float* lq0    = logits + T;                // T floats
  int*   starts = (int*)(lq0 + T);           // B+1 ints (padded)
  float* P      = (float*)(starts + 1028);   // 24 floats (padded to 32)
  unsigned short* w1b = (unsigned short*)(P + 32);  // 512*256 bf16

  k_bounds<<<dim3((BB+1+255)/256), 256, 0, stream>>>(batch, T, starts);
  k_params<<<1, 64, 0, stream>>>(rho, a1, a2, a3, P);
  k_castw<<<64, 256, 0, stream>>>(W1, w1b);
  hipMemsetAsync(logits, 0, (size_t)T*sizeof(float), stream);
  k_mlp<<<dim3(2, (T+63)/64), 256, 0, stream>>>(x, w1b, W2, logits, T);
  k_seg_softmax<<<BB, 64, 0, stream>>>(logits, starts, lq0);
  k_solver<<<BB, 1024, 0, stream>>>(x, lq0, starts, P, out);
}